// Round 1
// baseline (230.376 us; speedup 1.0000x reference)
//
#include <hip/hip_runtime.h>

// ShiftedPatchTokenization on MI355X (gfx950)
// x[64,3,224,224] f32 -> out[64,196,768] f32
// Pipeline: fold_w -> gvec -> pack (V bf16 + LN stats) -> MFMA GEMM with fused LN+bias epilogue.

typedef short bf16x8 __attribute__((ext_vector_type(8)));
typedef unsigned short u16x8 __attribute__((ext_vector_type(8)));
typedef float f32x4 __attribute__((ext_vector_type(4)));

#define GLOBAL_AS __attribute__((address_space(1)))
#define LDS_AS __attribute__((address_space(3)))

__device__ __forceinline__ unsigned short f2bf(float f) {
  union { float f; unsigned int u; } v;
  v.f = f;
  unsigned int u = v.u;
  unsigned int r = (u + 0x7FFFu + ((u >> 16) & 1u)) >> 16;  // RNE
  return (unsigned short)r;
}

// ---------------------------------------------------------------------------
// Kernel 1: fold gamma*w over duplicated shift groups, write transposed bf16
// w2t[768][2304]:  f2 = g*768 + c*256 + p1*16 + p2 ; g=0:x, g=1:left(x2), g=2:right(x2)
// grid (144, 3), block 256
// ---------------------------------------------------------------------------
__global__ __launch_bounds__(256) void spt_fold_w(
    const float* __restrict__ gamma, const float* __restrict__ w,
    unsigned short* __restrict__ w2t)
{
  __shared__ float tile[16][257];
  const int f2blk = blockIdx.x * 16;
  const int jblk  = blockIdx.y * 256;
  const int t = threadIdx.x;
  const int j = jblk + t;
  #pragma unroll
  for (int i = 0; i < 16; ++i) {
    const int f2 = f2blk + i;
    const int g = f2 / 768;
    const int rem = f2 % 768;  // c*256 + p1*16 + p2
    float v;
    if (g == 0) {
      const int f = rem;
      v = gamma[f] * w[(size_t)f * 768 + j];
    } else if (g == 1) {
      const int fa = 768 + rem, fb = 2304 + rem;   // left_up, left_down
      v = gamma[fa] * w[(size_t)fa * 768 + j] + gamma[fb] * w[(size_t)fb * 768 + j];
    } else {
      const int fa = 1536 + rem, fb = 3072 + rem;  // right_up, right_down
      v = gamma[fa] * w[(size_t)fa * 768 + j] + gamma[fb] * w[(size_t)fb * 768 + j];
    }
    tile[i][t] = v;
  }
  __syncthreads();
  u16x8 lo, hi;
  #pragma unroll
  for (int i = 0; i < 8; ++i) {
    lo[i] = f2bf(tile[i][t]);
    hi[i] = f2bf(tile[8 + i][t]);
  }
  unsigned short* dst = w2t + (size_t)j * 2304 + f2blk;
  *(u16x8*)dst = lo;
  *(u16x8*)(dst + 8) = hi;
}

// ---------------------------------------------------------------------------
// Kernel 2: G[j] = sum_f gamma[f] w[f][j];  Bt[j] = sum_f beta[f] w[f][j] + b[j]
// grid 12, block 256
// ---------------------------------------------------------------------------
__global__ __launch_bounds__(256) void spt_gvec(
    const float* __restrict__ gamma, const float* __restrict__ beta,
    const float* __restrict__ w, const float* __restrict__ bvec,
    float* __restrict__ G, float* __restrict__ Bt)
{
  __shared__ float gs[4][64], bs[4][64];
  const int jb = blockIdx.x * 64;
  const int t = threadIdx.x;
  const int j = jb + (t & 63);
  const int part = t >> 6;
  float g = 0.f, bt = 0.f;
  for (int f = part * 960; f < part * 960 + 960; ++f) {
    const float wv = w[(size_t)f * 768 + j];
    g  += gamma[f] * wv;
    bt += beta[f] * wv;
  }
  gs[part][t & 63] = g;
  bs[part][t & 63] = bt;
  __syncthreads();
  if (t < 64) {
    G[jb + t]  = gs[0][t] + gs[1][t] + gs[2][t] + gs[3][t];
    Bt[jb + t] = bs[0][t] + bs[1][t] + bs[2][t] + bs[3][t] + bvec[jb + t];
  }
}

// ---------------------------------------------------------------------------
// Kernel 3: pack V[12544][2304] bf16 + per-token LN stats (r, -mu*r)
// One block per (b, hi).  t<224: wi = t%14, p2 = t/14, reads full image rows.
// right[y,x'] = (1-t)*x[y,x'+8] + t*x[y+1,x'+8]   (0 if x'+8>=224; 2nd term 0 if y+1>=224)
// left [y,x'] = t*x[y-1,x'-8]  + (1-t)*x[y,x'-8]  (0 if x'-8<0;   1st term 0 if y<1)
// grid 896 (= 64*14), block 256
// ---------------------------------------------------------------------------
__global__ __launch_bounds__(256) void spt_pack(
    const float* __restrict__ x, unsigned short* __restrict__ V,
    float2* __restrict__ stats)
{
  __shared__ unsigned short slab[14][2312];  // +8 pad
  __shared__ float rsum[224], rsq[224];
  const int bi = blockIdx.x;
  const int b = bi / 14, hi = bi % 14;
  const int t = threadIdx.x;
  const float TW = 16.0f / 224.0f;
  float s = 0.f, q = 0.f;
  const int wi = t % 14, p2 = t / 14;  // valid for t<224
  for (int c = 0; c < 3; ++c) {
    const float* xc = x + ((size_t)(b * 3 + c)) * 224 * 224;
    for (int p1 = 0; p1 < 16; ++p1) {
      const int y = p1 * 14 + hi;
      if (t < 224) {
        const float* row = xc + (size_t)y * 224;
        const float xv = row[t];
        float rv = 0.f;
        if (t + 8 < 224) {
          rv = (1.0f - TW) * row[t + 8];
          if (y + 1 < 224) rv += TW * row[t + 8 + 224];
        }
        float lv = 0.f;
        if (t >= 8) {
          lv = (1.0f - TW) * row[t - 8];
          if (y >= 1) lv += TW * row[t - 8 - 224];
        }
        const int base = c * 256 + p1 * 16 + p2;
        slab[wi][base]        = f2bf(xv);
        slab[wi][768 + base]  = f2bf(lv);
        slab[wi][1536 + base] = f2bf(rv);
        s += xv + 2.f * (lv + rv);
        q += xv * xv + 2.f * (lv * lv + rv * rv);
      }
    }
  }
  if (t < 224) { rsum[t] = s; rsq[t] = q; }
  __syncthreads();
  const int tok0 = b * 196 + hi * 14;
  for (int i = t; i < 14 * 288; i += 256) {
    const int wi2 = i / 288, off = i % 288;
    const u16x8 v = *(const u16x8*)&slab[wi2][off * 8];
    *(u16x8*)&V[(size_t)(tok0 + wi2) * 2304 + off * 8] = v;
  }
  if (t < 14) {
    float S = 0.f, Q = 0.f;
    #pragma unroll
    for (int p = 0; p < 16; ++p) { S += rsum[t + 14 * p]; Q += rsq[t + 14 * p]; }
    const float mu = S / 3840.f;
    const float var = Q / 3840.f - mu * mu;
    const float r = rsqrtf(var + 1e-5f);
    stats[tok0 + t] = make_float2(r, -mu * r);
  }
}

// ---------------------------------------------------------------------------
// Kernel 4: GEMM  out[m][j] = r_m * (V[m,:] . w2t[j,:]) + (-mu*r)_m * G[j] + Bt[j]
// 128x128 tile, BK=64, 4 waves (2x2 of 64x64), mfma_f32_16x16x32_bf16.
// global_load_lds w=16 with pre-swizzled source; XOR-swizzled ds_read_b128
// (byte ^= (row&7)<<4) -> conflict-free.
// grid (98, 6), block 256
// ---------------------------------------------------------------------------
__global__ __launch_bounds__(256) void spt_gemm(
    const unsigned short* __restrict__ V, const unsigned short* __restrict__ w2t,
    const float2* __restrict__ stats, const float* __restrict__ G,
    const float* __restrict__ Bt, float* __restrict__ out)
{
  __shared__ unsigned short Alds[128 * 64];
  __shared__ unsigned short Blds[128 * 64];
  const int m0 = blockIdx.x * 128;
  const int n0 = blockIdx.y * 128;
  const int t = threadIdx.x;
  const int w = t >> 6;
  const int l = t & 63;
  const int wr = w >> 1, wc = w & 1;

  f32x4 acc[4][4] = {};

  const int row8 = l >> 3;                 // 0..7 within an 8-row staging slab
  const int srcel = ((l & 7) ^ row8) << 3; // pre-swizzled source k-element offset

  for (int kt = 0; kt < 36; ++kt) {
    const int k0 = kt << 6;
    #pragma unroll
    for (int i = 0; i < 4; ++i) {
      const int row = w * 32 + i * 8 + row8;
      const unsigned short* ga = V   + (size_t)(m0 + row) * 2304 + k0 + srcel;
      const unsigned short* gb = w2t + (size_t)(n0 + row) * 2304 + k0 + srcel;
      __builtin_amdgcn_global_load_lds((const GLOBAL_AS unsigned int*)ga,
                                       (LDS_AS unsigned int*)&Alds[(w * 32 + i * 8) * 64],
                                       16, 0, 0);
      __builtin_amdgcn_global_load_lds((const GLOBAL_AS unsigned int*)gb,
                                       (LDS_AS unsigned int*)&Blds[(w * 32 + i * 8) * 64],
                                       16, 0, 0);
    }
    __syncthreads();  // drains vmcnt -> tiles ready
    #pragma unroll
    for (int kk = 0; kk < 2; ++kk) {
      bf16x8 aF[4], bF[4];
      const int lane15 = l & 15;
      const int kb = kk * 64 + ((l >> 4) << 4);  // logical k-byte
      #pragma unroll
      for (int m = 0; m < 4; ++m) {
        const int row = wr * 64 + m * 16 + lane15;
        const int phys = row * 128 + (kb ^ ((row & 7) << 4));
        aF[m] = *(const bf16x8*)&Alds[phys >> 1];
      }
      #pragma unroll
      for (int n = 0; n < 4; ++n) {
        const int row = wc * 64 + n * 16 + lane15;
        const int phys = row * 128 + (kb ^ ((row & 7) << 4));
        bF[n] = *(const bf16x8*)&Blds[phys >> 1];
      }
      #pragma unroll
      for (int m = 0; m < 4; ++m)
        #pragma unroll
        for (int n = 0; n < 4; ++n)
          acc[m][n] = __builtin_amdgcn_mfma_f32_16x16x32_bf16(aF[m], bF[n], acc[m][n], 0, 0, 0);
    }
    __syncthreads();  // compute done before next overwrite
  }

  // Epilogue: C/D frag layout col = l&15, row = (l>>4)*4 + reg
  const int lane15 = l & 15;
  const int lg = (l >> 4) * 4;
  #pragma unroll
  for (int m = 0; m < 4; ++m) {
    const int rowb = m0 + wr * 64 + m * 16 + lg;
    float2 st[4];
    #pragma unroll
    for (int r = 0; r < 4; ++r) st[r] = stats[rowb + r];
    #pragma unroll
    for (int n = 0; n < 4; ++n) {
      const int col = n0 + wc * 64 + n * 16 + lane15;
      const float Gc = G[col];
      const float Bc = Bt[col];
      #pragma unroll
      for (int r = 0; r < 4; ++r) {
        out[(size_t)(rowb + r) * 768 + col] = st[r].x * acc[m][n][r] + st[r].y * Gc + Bc;
      }
    }
  }
}

// ---------------------------------------------------------------------------
// Workspace layout (bytes):
//   V     : 0                 12544*2304*2 = 57,802,752
//   w2t   : 57,802,752        768*2304*2   =  3,538,944
//   stats : 61,341,696        12544*8      =    100,352
//   G     : 61,442,048        768*4
//   Bt    : 61,445,120        768*4        -> total 61,448,192
// ---------------------------------------------------------------------------
extern "C" void kernel_launch(void* const* d_in, const int* in_sizes, int n_in,
                              void* d_out, int out_size, void* d_ws, size_t ws_size,
                              hipStream_t stream) {
  const float* x     = (const float*)d_in[0];
  const float* gamma = (const float*)d_in[1];
  const float* beta  = (const float*)d_in[2];
  const float* w     = (const float*)d_in[3];
  const float* bvec  = (const float*)d_in[4];
  float* out = (float*)d_out;

  char* ws = (char*)d_ws;
  unsigned short* V   = (unsigned short*)(ws);
  unsigned short* w2t = (unsigned short*)(ws + 57802752);
  float2* stats       = (float2*)(ws + 61341696);
  float* G            = (float*)(ws + 61442048);
  float* Bt           = (float*)(ws + 61445120);

  spt_fold_w<<<dim3(144, 3), 256, 0, stream>>>(gamma, w, w2t);
  spt_gvec<<<12, 256, 0, stream>>>(gamma, beta, w, bvec, G, Bt);
  spt_pack<<<896, 256, 0, stream>>>(x, V, stats);
  spt_gemm<<<dim3(98, 6), 256, 0, stream>>>(V, w2t, stats, G, Bt, out);
}

// Round 2
// 135.676 us; speedup vs baseline: 1.6980x; 1.6980x over previous
//
#include <hip/hip_runtime.h>

// ShiftedPatchTokenization on MI355X (gfx950)
// x[64,3,224,224] f32 -> out[64,196,768] f32
// Pipeline: fold_w (+G/Bt partials) -> gb reduce -> pack (vec4) -> MFMA GEMM w/ fused LN epilogue.

typedef short bf16x8 __attribute__((ext_vector_type(8)));
typedef unsigned short u16x8 __attribute__((ext_vector_type(8)));
typedef float f32x4 __attribute__((ext_vector_type(4)));

#define GLOBAL_AS __attribute__((address_space(1)))
#define LDS_AS __attribute__((address_space(3)))

__device__ __forceinline__ unsigned short f2bf(float f) {
  union { float f; unsigned int u; } v;
  v.f = f;
  unsigned int u = v.u;
  unsigned int r = (u + 0x7FFFu + ((u >> 16) & 1u)) >> 16;  // RNE
  return (unsigned short)r;
}

// ---------------------------------------------------------------------------
// Kernel 1: fold gamma*w over duplicated shift groups -> w2t[768][2304] bf16,
// plus per-f2-block partial sums  Gp[xblk][j] = sum gamma*w,  Bp = sum beta*w.
// grid (144, 3), block 256
// ---------------------------------------------------------------------------
__global__ __launch_bounds__(256) void spt_fold_w(
    const float* __restrict__ gamma, const float* __restrict__ beta,
    const float* __restrict__ w, unsigned short* __restrict__ w2t,
    float* __restrict__ Gp, float* __restrict__ Bp)
{
  __shared__ float tile[16][257];
  const int f2blk = blockIdx.x * 16;
  const int jblk  = blockIdx.y * 256;
  const int t = threadIdx.x;
  const int j = jblk + t;
  float gacc = 0.f, bacc = 0.f;
  #pragma unroll
  for (int i = 0; i < 16; ++i) {
    const int f2 = f2blk + i;
    const int g = f2 / 768;
    const int rem = f2 % 768;  // c*256 + p1*16 + p2
    float v, bv;
    if (g == 0) {
      const int f = rem;
      const float wv = w[(size_t)f * 768 + j];
      v = gamma[f] * wv;
      bv = beta[f] * wv;
    } else if (g == 1) {
      const int fa = 768 + rem, fb = 2304 + rem;   // left_up, left_down
      const float wa = w[(size_t)fa * 768 + j], wb = w[(size_t)fb * 768 + j];
      v = gamma[fa] * wa + gamma[fb] * wb;
      bv = beta[fa] * wa + beta[fb] * wb;
    } else {
      const int fa = 1536 + rem, fb = 3072 + rem;  // right_up, right_down
      const float wa = w[(size_t)fa * 768 + j], wb = w[(size_t)fb * 768 + j];
      v = gamma[fa] * wa + gamma[fb] * wb;
      bv = beta[fa] * wa + beta[fb] * wb;
    }
    tile[i][t] = v;
    gacc += v;
    bacc += bv;
  }
  __syncthreads();
  u16x8 lo, hi;
  #pragma unroll
  for (int i = 0; i < 8; ++i) {
    lo[i] = f2bf(tile[i][t]);
    hi[i] = f2bf(tile[8 + i][t]);
  }
  unsigned short* dst = w2t + (size_t)j * 2304 + f2blk;
  *(u16x8*)dst = lo;
  *(u16x8*)(dst + 8) = hi;
  Gp[blockIdx.x * 768 + j] = gacc;
  Bp[blockIdx.x * 768 + j] = bacc;
}

// ---------------------------------------------------------------------------
// Kernel 2: reduce 144 partials -> G[768], Bt[768] (+b). grid 3, block 256
// ---------------------------------------------------------------------------
__global__ __launch_bounds__(256) void spt_gb(
    const float* __restrict__ Gp, const float* __restrict__ Bp,
    const float* __restrict__ bvec, float* __restrict__ G, float* __restrict__ Bt)
{
  const int j = blockIdx.x * 256 + threadIdx.x;
  float g = 0.f, bb = 0.f;
  for (int i = 0; i < 144; ++i) {
    g += Gp[i * 768 + j];
    bb += Bp[i * 768 + j];
  }
  G[j] = g;
  Bt[j] = bb + bvec[j];
}

// ---------------------------------------------------------------------------
// Kernel 3: pack V[12544][2304] bf16 + per-token LN stats (r, -mu*r)
// Block per (b, hi). t<224: grp = t/56 in [0,4) owns 12 (c,p1) pairs;
// q = t%56 owns x4 = 4q..4q+3 (float4 lane). Shift +-8 is float4-aligned;
// right valid iff q<54, left valid iff q>=2 (whole-quad masks).
// grid 896, block 256
// ---------------------------------------------------------------------------
__global__ __launch_bounds__(256) void spt_pack(
    const float* __restrict__ x, unsigned short* __restrict__ V,
    float2* __restrict__ stats)
{
  __shared__ unsigned short slab[14 * 2312];  // token-major, +8 pad per row
  __shared__ float sred[4][224];
  __shared__ float qred[4][224];
  const int bi = blockIdx.x;
  const int b = bi / 14, hi = bi % 14;
  const int t = threadIdx.x;
  const float TW = 16.0f / 224.0f;

  const int q = t % 56;
  const int grp = t / 56;
  const int x4 = q * 4;

  int sloff[4];
  {
    int wi = x4 % 14, p2 = x4 / 14;
    #pragma unroll
    for (int j = 0; j < 4; ++j) {
      sloff[j] = wi * 2312 + p2;
      if (++wi == 14) { wi = 0; ++p2; }
    }
  }

  if (t < 224) {
    f32x4 sAcc = {0.f, 0.f, 0.f, 0.f}, qAcc = {0.f, 0.f, 0.f, 0.f};
    #pragma unroll
    for (int it = 0; it < 12; ++it) {
      const int cp = grp * 12 + it;
      const int c = cp >> 4, p1 = cp & 15;
      const int y = p1 * 14 + hi;
      const float* row = x + ((size_t)(b * 3 + c)) * 50176 + (size_t)y * 224;
      const f32x4 xv = *(const f32x4*)(row + x4);
      f32x4 ra = {0.f,0.f,0.f,0.f}, rb = {0.f,0.f,0.f,0.f};
      f32x4 la = {0.f,0.f,0.f,0.f}, lb = {0.f,0.f,0.f,0.f};
      if (q < 54) {
        ra = *(const f32x4*)(row + x4 + 8);
        if (y < 223) rb = *(const f32x4*)(row + x4 + 8 + 224);
      }
      if (q >= 2) {
        la = *(const f32x4*)(row + x4 - 8);
        if (y > 0) lb = *(const f32x4*)(row + x4 - 8 - 224);
      }
      const f32x4 rv = (1.0f - TW) * ra + TW * rb;
      const f32x4 lv = (1.0f - TW) * la + TW * lb;
      sAcc += xv + 2.0f * (lv + rv);
      qAcc += xv * xv + 2.0f * (lv * lv + rv * rv);
      const int kb = c * 256 + p1 * 16;
      #pragma unroll
      for (int j = 0; j < 4; ++j) {
        slab[sloff[j] + kb]        = f2bf(xv[j]);
        slab[sloff[j] + kb + 768]  = f2bf(lv[j]);
        slab[sloff[j] + kb + 1536] = f2bf(rv[j]);
      }
    }
    #pragma unroll
    for (int j = 0; j < 4; ++j) {
      sred[grp][x4 + j] = sAcc[j];
      qred[grp][x4 + j] = qAcc[j];
    }
  }
  __syncthreads();

  float ss = 0.f, qq = 0.f;
  if (t < 224) {
    ss = sred[0][t] + sred[1][t] + sred[2][t] + sred[3][t];
    qq = qred[0][t] + qred[1][t] + qred[2][t] + qred[3][t];
  }
  __syncthreads();
  if (t < 224) { sred[0][t] = ss; qred[0][t] = qq; }
  __syncthreads();

  const int tok0 = b * 196 + hi * 14;
  if (t < 14) {
    float S = 0.f, Q = 0.f;
    #pragma unroll
    for (int p = 0; p < 16; ++p) { S += sred[0][t + 14 * p]; Q += qred[0][t + 14 * p]; }
    const float mu = S / 3840.f;
    const float var = Q / 3840.f - mu * mu;
    const float r = rsqrtf(var + 1e-5f);
    stats[tok0 + t] = make_float2(r, -mu * r);
  }

  // write out V: thread (wi2, sub) copies 18 16B chunks of its token row
  if (t < 224) {
    const int wi2 = t >> 4, sub = t & 15;
    const size_t vbase = (size_t)(tok0 + wi2) * 2304;
    #pragma unroll
    for (int cc = 0; cc < 18; ++cc) {
      const int off8 = (cc * 16 + sub) * 8;
      *(u16x8*)&V[vbase + off8] = *(const u16x8*)&slab[wi2 * 2312 + off8];
    }
  }
}

// ---------------------------------------------------------------------------
// Kernel 4: GEMM  out[m][j] = r_m * (V[m,:] . w2t[j,:]) + (-mu*r)_m * G[j] + Bt[j]
// 128x128 tile, BK=64, 4 waves, mfma_f32_16x16x32_bf16.
// 1D grid 588 with bijective XCD-chunk swizzle (q=73, r=4), N-fastest decomp:
// the 6 N-tiles sharing an A-tile run temporally adjacent on one XCD.
// ---------------------------------------------------------------------------
__global__ __launch_bounds__(256) void spt_gemm(
    const unsigned short* __restrict__ V, const unsigned short* __restrict__ w2t,
    const float2* __restrict__ stats, const float* __restrict__ G,
    const float* __restrict__ Bt, float* __restrict__ out)
{
  __shared__ unsigned short Alds[128 * 64];
  __shared__ unsigned short Blds[128 * 64];
  const int orig = blockIdx.x;
  const int xcd = orig & 7;
  const int base = (xcd < 4) ? xcd * 74 : 4 * 74 + (xcd - 4) * 73;
  const int wgid = base + (orig >> 3);
  const int m0 = (wgid / 6) * 128;
  const int n0 = (wgid % 6) * 128;
  const int t = threadIdx.x;
  const int w = t >> 6;
  const int l = t & 63;
  const int wr = w >> 1, wc = w & 1;

  f32x4 acc[4][4] = {};

  const int row8 = l >> 3;                 // 0..7 within an 8-row staging slab
  const int srcel = ((l & 7) ^ row8) << 3; // pre-swizzled source k-element offset

  for (int kt = 0; kt < 36; ++kt) {
    const int k0 = kt << 6;
    #pragma unroll
    for (int i = 0; i < 4; ++i) {
      const int row = w * 32 + i * 8 + row8;
      const unsigned short* ga = V   + (size_t)(m0 + row) * 2304 + k0 + srcel;
      const unsigned short* gb = w2t + (size_t)(n0 + row) * 2304 + k0 + srcel;
      __builtin_amdgcn_global_load_lds((const GLOBAL_AS unsigned int*)ga,
                                       (LDS_AS unsigned int*)&Alds[(w * 32 + i * 8) * 64],
                                       16, 0, 0);
      __builtin_amdgcn_global_load_lds((const GLOBAL_AS unsigned int*)gb,
                                       (LDS_AS unsigned int*)&Blds[(w * 32 + i * 8) * 64],
                                       16, 0, 0);
    }
    __syncthreads();  // drains vmcnt -> tiles ready
    #pragma unroll
    for (int kk = 0; kk < 2; ++kk) {
      bf16x8 aF[4], bF[4];
      const int lane15 = l & 15;
      const int kb = kk * 64 + ((l >> 4) << 4);  // logical k-byte
      #pragma unroll
      for (int m = 0; m < 4; ++m) {
        const int row = wr * 64 + m * 16 + lane15;
        const int phys = row * 128 + (kb ^ ((row & 7) << 4));
        aF[m] = *(const bf16x8*)&Alds[phys >> 1];
      }
      #pragma unroll
      for (int n = 0; n < 4; ++n) {
        const int row = wc * 64 + n * 16 + lane15;
        const int phys = row * 128 + (kb ^ ((row & 7) << 4));
        bF[n] = *(const bf16x8*)&Blds[phys >> 1];
      }
      #pragma unroll
      for (int m = 0; m < 4; ++m)
        #pragma unroll
        for (int n = 0; n < 4; ++n)
          acc[m][n] = __builtin_amdgcn_mfma_f32_16x16x32_bf16(aF[m], bF[n], acc[m][n], 0, 0, 0);
    }
    __syncthreads();  // compute done before next overwrite
  }

  // Epilogue: C/D frag layout col = l&15, row = (l>>4)*4 + reg
  const int lane15 = l & 15;
  const int lg = (l >> 4) * 4;
  #pragma unroll
  for (int m = 0; m < 4; ++m) {
    const int rowb = m0 + wr * 64 + m * 16 + lg;
    float2 st[4];
    #pragma unroll
    for (int r = 0; r < 4; ++r) st[r] = stats[rowb + r];
    #pragma unroll
    for (int n = 0; n < 4; ++n) {
      const int col = n0 + wc * 64 + n * 16 + lane15;
      const float Gc = G[col];
      const float Bc = Bt[col];
      #pragma unroll
      for (int r = 0; r < 4; ++r) {
        out[(size_t)(rowb + r) * 768 + col] = st[r].x * acc[m][n][r] + st[r].y * Gc + Bc;
      }
    }
  }
}

// ---------------------------------------------------------------------------
// Workspace layout (bytes):
//   V     : 0            57,802,752
//   w2t   : 57,802,752    3,538,944
//   stats : 61,341,696      100,352
//   G     : 61,442,048        3,072
//   Bt    : 61,445,120        3,072
//   Gp    : 61,448,192      442,368
//   Bp    : 61,890,560      442,368   -> total 62,332,928
// ---------------------------------------------------------------------------
extern "C" void kernel_launch(void* const* d_in, const int* in_sizes, int n_in,
                              void* d_out, int out_size, void* d_ws, size_t ws_size,
                              hipStream_t stream) {
  const float* x     = (const float*)d_in[0];
  const float* gamma = (const float*)d_in[1];
  const float* beta  = (const float*)d_in[2];
  const float* w     = (const float*)d_in[3];
  const float* bvec  = (const float*)d_in[4];
  float* out = (float*)d_out;

  char* ws = (char*)d_ws;
  unsigned short* V   = (unsigned short*)(ws);
  unsigned short* w2t = (unsigned short*)(ws + 57802752);
  float2* stats       = (float2*)(ws + 61341696);
  float* G            = (float*)(ws + 61442048);
  float* Bt           = (float*)(ws + 61445120);
  float* Gp           = (float*)(ws + 61448192);
  float* Bp           = (float*)(ws + 61890560);

  spt_pack<<<896, 256, 0, stream>>>(x, V, stats);
  spt_fold_w<<<dim3(144, 3), 256, 0, stream>>>(gamma, beta, w, w2t, Gp, Bp);
  spt_gb<<<3, 256, 0, stream>>>(Gp, Bp, bvec, G, Bt);
  spt_gemm<<<588, 256, 0, stream>>>(V, w2t, stats, G, Bt, out);
}

// Round 3
// 123.485 us; speedup vs baseline: 1.8656x; 1.0987x over previous
//
#include <hip/hip_runtime.h>

// ShiftedPatchTokenization on MI355X (gfx950)
// x[64,3,224,224] f32 -> out[64,196,768] f32
// Pipeline: fold_w (+G/Bt partials) -> gb reduce -> pack (vec4) -> 256x256 dbuf MFMA GEMM.

typedef short bf16x8 __attribute__((ext_vector_type(8)));
typedef unsigned short u16x8 __attribute__((ext_vector_type(8)));
typedef float f32x4 __attribute__((ext_vector_type(4)));

#define GLOBAL_AS __attribute__((address_space(1)))
#define LDS_AS __attribute__((address_space(3)))

__device__ __forceinline__ unsigned short f2bf(float f) {
  union { float f; unsigned int u; } v;
  v.f = f;
  unsigned int u = v.u;
  unsigned int r = (u + 0x7FFFu + ((u >> 16) & 1u)) >> 16;  // RNE
  return (unsigned short)r;
}

// ---------------------------------------------------------------------------
// Kernel 1: fold gamma*w over duplicated shift groups -> w2t[768][2304] bf16,
// plus per-f2-block partial sums  Gp[xblk][j] = sum gamma*w,  Bp = sum beta*w.
// grid (144, 3), block 256
// ---------------------------------------------------------------------------
__global__ __launch_bounds__(256) void spt_fold_w(
    const float* __restrict__ gamma, const float* __restrict__ beta,
    const float* __restrict__ w, unsigned short* __restrict__ w2t,
    float* __restrict__ Gp, float* __restrict__ Bp)
{
  __shared__ float tile[16][257];
  const int f2blk = blockIdx.x * 16;
  const int jblk  = blockIdx.y * 256;
  const int t = threadIdx.x;
  const int j = jblk + t;
  float gacc = 0.f, bacc = 0.f;
  #pragma unroll
  for (int i = 0; i < 16; ++i) {
    const int f2 = f2blk + i;
    const int g = f2 / 768;
    const int rem = f2 % 768;  // c*256 + p1*16 + p2
    float v, bv;
    if (g == 0) {
      const int f = rem;
      const float wv = w[(size_t)f * 768 + j];
      v = gamma[f] * wv;
      bv = beta[f] * wv;
    } else if (g == 1) {
      const int fa = 768 + rem, fb = 2304 + rem;   // left_up, left_down
      const float wa = w[(size_t)fa * 768 + j], wb = w[(size_t)fb * 768 + j];
      v = gamma[fa] * wa + gamma[fb] * wb;
      bv = beta[fa] * wa + beta[fb] * wb;
    } else {
      const int fa = 1536 + rem, fb = 3072 + rem;  // right_up, right_down
      const float wa = w[(size_t)fa * 768 + j], wb = w[(size_t)fb * 768 + j];
      v = gamma[fa] * wa + gamma[fb] * wb;
      bv = beta[fa] * wa + beta[fb] * wb;
    }
    tile[i][t] = v;
    gacc += v;
    bacc += bv;
  }
  __syncthreads();
  u16x8 lo, hi;
  #pragma unroll
  for (int i = 0; i < 8; ++i) {
    lo[i] = f2bf(tile[i][t]);
    hi[i] = f2bf(tile[8 + i][t]);
  }
  unsigned short* dst = w2t + (size_t)j * 2304 + f2blk;
  *(u16x8*)dst = lo;
  *(u16x8*)(dst + 8) = hi;
  Gp[blockIdx.x * 768 + j] = gacc;
  Bp[blockIdx.x * 768 + j] = bacc;
}

// ---------------------------------------------------------------------------
// Kernel 2: reduce 144 partials -> G[768], Bt[768] (+b). grid 3, block 256
// ---------------------------------------------------------------------------
__global__ __launch_bounds__(256) void spt_gb(
    const float* __restrict__ Gp, const float* __restrict__ Bp,
    const float* __restrict__ bvec, float* __restrict__ G, float* __restrict__ Bt)
{
  const int j = blockIdx.x * 256 + threadIdx.x;
  float g = 0.f, bb = 0.f;
  for (int i = 0; i < 144; ++i) {
    g += Gp[i * 768 + j];
    bb += Bp[i * 768 + j];
  }
  G[j] = g;
  Bt[j] = bb + bvec[j];
}

// ---------------------------------------------------------------------------
// Kernel 3: pack V[12544][2304] bf16 + per-token LN stats (r, -mu*r)
// grid 896, block 256
// ---------------------------------------------------------------------------
__global__ __launch_bounds__(256) void spt_pack(
    const float* __restrict__ x, unsigned short* __restrict__ V,
    float2* __restrict__ stats)
{
  __shared__ unsigned short slab[14 * 2312];  // token-major, +8 pad per row
  __shared__ float sred[4][224];
  __shared__ float qred[4][224];
  const int bi = blockIdx.x;
  const int b = bi / 14, hi = bi % 14;
  const int t = threadIdx.x;
  const float TW = 16.0f / 224.0f;

  const int q = t % 56;
  const int grp = t / 56;
  const int x4 = q * 4;

  int sloff[4];
  {
    int wi = x4 % 14, p2 = x4 / 14;
    #pragma unroll
    for (int j = 0; j < 4; ++j) {
      sloff[j] = wi * 2312 + p2;
      if (++wi == 14) { wi = 0; ++p2; }
    }
  }

  if (t < 224) {
    f32x4 sAcc = {0.f, 0.f, 0.f, 0.f}, qAcc = {0.f, 0.f, 0.f, 0.f};
    #pragma unroll
    for (int it = 0; it < 12; ++it) {
      const int cp = grp * 12 + it;
      const int c = cp >> 4, p1 = cp & 15;
      const int y = p1 * 14 + hi;
      const float* row = x + ((size_t)(b * 3 + c)) * 50176 + (size_t)y * 224;
      const f32x4 xv = *(const f32x4*)(row + x4);
      f32x4 ra = {0.f,0.f,0.f,0.f}, rb = {0.f,0.f,0.f,0.f};
      f32x4 la = {0.f,0.f,0.f,0.f}, lb = {0.f,0.f,0.f,0.f};
      if (q < 54) {
        ra = *(const f32x4*)(row + x4 + 8);
        if (y < 223) rb = *(const f32x4*)(row + x4 + 8 + 224);
      }
      if (q >= 2) {
        la = *(const f32x4*)(row + x4 - 8);
        if (y > 0) lb = *(const f32x4*)(row + x4 - 8 - 224);
      }
      const f32x4 rv = (1.0f - TW) * ra + TW * rb;
      const f32x4 lv = (1.0f - TW) * la + TW * lb;
      sAcc += xv + 2.0f * (lv + rv);
      qAcc += xv * xv + 2.0f * (lv * lv + rv * rv);
      const int kb = c * 256 + p1 * 16;
      #pragma unroll
      for (int j = 0; j < 4; ++j) {
        slab[sloff[j] + kb]        = f2bf(xv[j]);
        slab[sloff[j] + kb + 768]  = f2bf(lv[j]);
        slab[sloff[j] + kb + 1536] = f2bf(rv[j]);
      }
    }
    #pragma unroll
    for (int j = 0; j < 4; ++j) {
      sred[grp][x4 + j] = sAcc[j];
      qred[grp][x4 + j] = qAcc[j];
    }
  }
  __syncthreads();

  float ss = 0.f, qq = 0.f;
  if (t < 224) {
    ss = sred[0][t] + sred[1][t] + sred[2][t] + sred[3][t];
    qq = qred[0][t] + qred[1][t] + qred[2][t] + qred[3][t];
  }
  __syncthreads();
  if (t < 224) { sred[0][t] = ss; qred[0][t] = qq; }
  __syncthreads();

  const int tok0 = b * 196 + hi * 14;
  if (t < 14) {
    float S = 0.f, Q = 0.f;
    #pragma unroll
    for (int p = 0; p < 16; ++p) { S += sred[0][t + 14 * p]; Q += qred[0][t + 14 * p]; }
    const float mu = S / 3840.f;
    const float var = Q / 3840.f - mu * mu;
    const float r = rsqrtf(var + 1e-5f);
    stats[tok0 + t] = make_float2(r, -mu * r);
  }

  if (t < 224) {
    const int wi2 = t >> 4, sub = t & 15;
    const size_t vbase = (size_t)(tok0 + wi2) * 2304;
    #pragma unroll
    for (int cc = 0; cc < 18; ++cc) {
      const int off8 = (cc * 16 + sub) * 8;
      *(u16x8*)&V[vbase + off8] = *(const u16x8*)&slab[wi2 * 2312 + off8];
    }
  }
}

// ---------------------------------------------------------------------------
// Kernel 4: GEMM  out[m][j] = r_m * (V[m,:] . w2t[j,:]) + (-mu*r)_m * G[j] + Bt[j]
// 256x256 tile, BK=64, 8 waves (2M x 4N, each 128x64 out), double-buffered
// 128 KiB LDS, counted s_waitcnt vmcnt(8) (never drain-0 in main loop),
// raw s_barrier, conflict-free XOR swizzle (byte ^= (row&7)<<4) with
// pre-swizzled global source. grid 147 (= 49x3, one block per CU),
// bijective XCD swizzle (q=18, r=3), N-fastest.
// ---------------------------------------------------------------------------
__global__ __launch_bounds__(512, 2) void spt_gemm(
    const unsigned short* __restrict__ V, const unsigned short* __restrict__ w2t,
    const float2* __restrict__ stats, const float* __restrict__ G,
    const float* __restrict__ Bt, float* __restrict__ out)
{
  __shared__ unsigned short Alds[2][256 * 64];
  __shared__ unsigned short Blds[2][256 * 64];

  const int orig = blockIdx.x;
  const int xcd = orig & 7, loc = orig >> 3;
  const int wgid = (xcd < 3 ? xcd * 19 : 57 + (xcd - 3) * 18) + loc;  // bijective, nwg=147
  const int m0 = (wgid / 3) * 256;
  const int n0 = (wgid % 3) * 256;
  const int t = threadIdx.x;
  const int w = t >> 6, l = t & 63;
  const int wr = w >> 2;   // 0..1 -> 128-row half
  const int wn = w & 3;    // 0..3 -> 64-col slice

  f32x4 acc[8][4] = {};

  // Staging: thread t, load i stages row = i*64 + (t>>3), 16B chunk (t&7).
  // Pre-swizzled source so linear LDS dest + swizzled read agree.
  const int srow = t >> 3;
  const int srcel = (((t & 7) ^ (srow & 7)) << 3);

#define STAGE(pb, kt)                                                          \
  {                                                                            \
    const int k0s = (kt) << 6;                                                 \
    _Pragma("unroll") for (int i = 0; i < 4; ++i) {                            \
      const int row = i * 64 + srow;                                           \
      const unsigned short* ga = V + (size_t)(m0 + row) * 2304 + k0s + srcel;  \
      const unsigned short* gb = w2t + (size_t)(n0 + row) * 2304 + k0s + srcel;\
      __builtin_amdgcn_global_load_lds((const GLOBAL_AS unsigned int*)ga,      \
          (LDS_AS unsigned int*)&Alds[pb][i * 4096 + w * 512], 16, 0, 0);      \
      __builtin_amdgcn_global_load_lds((const GLOBAL_AS unsigned int*)gb,      \
          (LDS_AS unsigned int*)&Blds[pb][i * 4096 + w * 512], 16, 0, 0);      \
    }                                                                          \
  }

#define COMPUTE(pb)                                                            \
  {                                                                            \
    const int lane15 = l & 15;                                                 \
    const int kcol = (l >> 4) << 4;                                            \
    _Pragma("unroll") for (int kk = 0; kk < 2; ++kk) {                         \
      const int kb = kk * 64 + kcol;                                           \
      bf16x8 bF[4];                                                            \
      _Pragma("unroll") for (int n = 0; n < 4; ++n) {                          \
        const int row = wn * 64 + n * 16 + lane15;                             \
        const int phys = row * 128 + (kb ^ ((row & 7) << 4));                  \
        bF[n] = *(const bf16x8*)&Blds[pb][phys >> 1];                          \
      }                                                                        \
      _Pragma("unroll") for (int m = 0; m < 8; ++m) {                          \
        const int row = wr * 128 + m * 16 + lane15;                            \
        const int phys = row * 128 + (kb ^ ((row & 7) << 4));                  \
        const bf16x8 aF = *(const bf16x8*)&Alds[pb][phys >> 1];                \
        _Pragma("unroll") for (int n = 0; n < 4; ++n)                          \
          acc[m][n] = __builtin_amdgcn_mfma_f32_16x16x32_bf16(aF, bF[n],       \
                                                              acc[m][n], 0, 0, 0); \
      }                                                                        \
    }                                                                          \
  }

  STAGE(0, 0);
  int pb = 0;
  for (int kt = 0; kt < 35; ++kt) {
    STAGE(pb ^ 1, kt + 1);
    // wait for the 8 oldest loads (step kt); 8 newest (kt+1) stay in flight
    asm volatile("s_waitcnt vmcnt(8)\n\ts_barrier" ::: "memory");
    COMPUTE(pb);
    asm volatile("s_barrier" ::: "memory");  // reads of buf pb done before it's restaged
    pb ^= 1;
  }
  asm volatile("s_waitcnt vmcnt(0)\n\ts_barrier" ::: "memory");
  COMPUTE(pb);

  // Epilogue: C/D frag layout col = l&15, row = (l>>4)*4 + reg
  const int lane15 = l & 15;
  const int lg = (l >> 4) * 4;
  #pragma unroll
  for (int m = 0; m < 8; ++m) {
    const int rowb = m0 + wr * 128 + m * 16 + lg;
    float2 st[4];
    #pragma unroll
    for (int r = 0; r < 4; ++r) st[r] = stats[rowb + r];
    #pragma unroll
    for (int n = 0; n < 4; ++n) {
      const int col = n0 + wn * 64 + n * 16 + lane15;
      const float Gc = G[col];
      const float Bc = Bt[col];
      #pragma unroll
      for (int r = 0; r < 4; ++r) {
        out[(size_t)(rowb + r) * 768 + col] = st[r].x * acc[m][n][r] + st[r].y * Gc + Bc;
      }
    }
  }
#undef STAGE
#undef COMPUTE
}

// ---------------------------------------------------------------------------
// Workspace layout (bytes):
//   V     : 0            57,802,752
//   w2t   : 57,802,752    3,538,944
//   stats : 61,341,696      100,352
//   G     : 61,442,048        3,072
//   Bt    : 61,445,120        3,072
//   Gp    : 61,448,192      442,368
//   Bp    : 61,890,560      442,368   -> total 62,332,928
// ---------------------------------------------------------------------------
extern "C" void kernel_launch(void* const* d_in, const int* in_sizes, int n_in,
                              void* d_out, int out_size, void* d_ws, size_t ws_size,
                              hipStream_t stream) {
  const float* x     = (const float*)d_in[0];
  const float* gamma = (const float*)d_in[1];
  const float* beta  = (const float*)d_in[2];
  const float* w     = (const float*)d_in[3];
  const float* bvec  = (const float*)d_in[4];
  float* out = (float*)d_out;

  char* ws = (char*)d_ws;
  unsigned short* V   = (unsigned short*)(ws);
  unsigned short* w2t = (unsigned short*)(ws + 57802752);
  float2* stats       = (float2*)(ws + 61341696);
  float* G            = (float*)(ws + 61442048);
  float* Bt           = (float*)(ws + 61445120);
  float* Gp           = (float*)(ws + 61448192);
  float* Bp           = (float*)(ws + 61890560);

  spt_pack<<<896, 256, 0, stream>>>(x, V, stats);
  spt_fold_w<<<dim3(144, 3), 256, 0, stream>>>(gamma, beta, w, w2t, Gp, Bp);
  spt_gb<<<3, 256, 0, stream>>>(Gp, Bp, bvec, G, Bt);
  spt_gemm<<<147, 512, 0, stream>>>(V, w2t, stats, G, Bt, out);
}

// Round 4
// 101.420 us; speedup vs baseline: 2.2715x; 1.2176x over previous
//
#include <hip/hip_runtime.h>

// ShiftedPatchTokenization on MI355X (gfx950)
// x[64,3,224,224] f32 -> out[64,196,768] f32
// Pipeline: fold_w (+G/Bt partials) -> gb reduce -> pack (vec4) -> 224x96 dbuf MFMA GEMM.

typedef short bf16x8 __attribute__((ext_vector_type(8)));
typedef unsigned short u16x8 __attribute__((ext_vector_type(8)));
typedef float f32x4 __attribute__((ext_vector_type(4)));

#define GLOBAL_AS __attribute__((address_space(1)))
#define LDS_AS __attribute__((address_space(3)))

__device__ __forceinline__ unsigned short f2bf(float f) {
  union { float f; unsigned int u; } v;
  v.f = f;
  unsigned int u = v.u;
  unsigned int r = (u + 0x7FFFu + ((u >> 16) & 1u)) >> 16;  // RNE
  return (unsigned short)r;
}

// ---------------------------------------------------------------------------
// Kernel 1: fold gamma*w over duplicated shift groups -> w2t[768][2304] bf16,
// plus per-f2-block partial sums  Gp[xblk][j] = sum gamma*w,  Bp = sum beta*w.
// grid (144, 3), block 256
// ---------------------------------------------------------------------------
__global__ __launch_bounds__(256) void spt_fold_w(
    const float* __restrict__ gamma, const float* __restrict__ beta,
    const float* __restrict__ w, unsigned short* __restrict__ w2t,
    float* __restrict__ Gp, float* __restrict__ Bp)
{
  __shared__ float tile[16][257];
  const int f2blk = blockIdx.x * 16;
  const int jblk  = blockIdx.y * 256;
  const int t = threadIdx.x;
  const int j = jblk + t;
  float gacc = 0.f, bacc = 0.f;
  #pragma unroll
  for (int i = 0; i < 16; ++i) {
    const int f2 = f2blk + i;
    const int g = f2 / 768;
    const int rem = f2 % 768;  // c*256 + p1*16 + p2
    float v, bv;
    if (g == 0) {
      const int f = rem;
      const float wv = w[(size_t)f * 768 + j];
      v = gamma[f] * wv;
      bv = beta[f] * wv;
    } else if (g == 1) {
      const int fa = 768 + rem, fb = 2304 + rem;   // left_up, left_down
      const float wa = w[(size_t)fa * 768 + j], wb = w[(size_t)fb * 768 + j];
      v = gamma[fa] * wa + gamma[fb] * wb;
      bv = beta[fa] * wa + beta[fb] * wb;
    } else {
      const int fa = 1536 + rem, fb = 3072 + rem;  // right_up, right_down
      const float wa = w[(size_t)fa * 768 + j], wb = w[(size_t)fb * 768 + j];
      v = gamma[fa] * wa + gamma[fb] * wb;
      bv = beta[fa] * wa + beta[fb] * wb;
    }
    tile[i][t] = v;
    gacc += v;
    bacc += bv;
  }
  __syncthreads();
  u16x8 lo, hi;
  #pragma unroll
  for (int i = 0; i < 8; ++i) {
    lo[i] = f2bf(tile[i][t]);
    hi[i] = f2bf(tile[8 + i][t]);
  }
  unsigned short* dst = w2t + (size_t)j * 2304 + f2blk;
  *(u16x8*)dst = lo;
  *(u16x8*)(dst + 8) = hi;
  Gp[blockIdx.x * 768 + j] = gacc;
  Bp[blockIdx.x * 768 + j] = bacc;
}

// ---------------------------------------------------------------------------
// Kernel 2: reduce 144 partials -> G[768], Bt[768] (+b). grid 3, block 256
// ---------------------------------------------------------------------------
__global__ __launch_bounds__(256) void spt_gb(
    const float* __restrict__ Gp, const float* __restrict__ Bp,
    const float* __restrict__ bvec, float* __restrict__ G, float* __restrict__ Bt)
{
  const int j = blockIdx.x * 256 + threadIdx.x;
  float g = 0.f, bb = 0.f;
  for (int i = 0; i < 144; ++i) {
    g += Gp[i * 768 + j];
    bb += Bp[i * 768 + j];
  }
  G[j] = g;
  Bt[j] = bb + bvec[j];
}

// ---------------------------------------------------------------------------
// Kernel 3: pack V[12544][2304] bf16 + per-token LN stats (r, -mu*r)
// grid 896, block 256
// ---------------------------------------------------------------------------
__global__ __launch_bounds__(256) void spt_pack(
    const float* __restrict__ x, unsigned short* __restrict__ V,
    float2* __restrict__ stats)
{
  __shared__ unsigned short slab[14 * 2312];  // token-major, +8 pad per row
  __shared__ float sred[4][224];
  __shared__ float qred[4][224];
  const int bi = blockIdx.x;
  const int b = bi / 14, hi = bi % 14;
  const int t = threadIdx.x;
  const float TW = 16.0f / 224.0f;

  const int q = t % 56;
  const int grp = t / 56;
  const int x4 = q * 4;

  int sloff[4];
  {
    int wi = x4 % 14, p2 = x4 / 14;
    #pragma unroll
    for (int j = 0; j < 4; ++j) {
      sloff[j] = wi * 2312 + p2;
      if (++wi == 14) { wi = 0; ++p2; }
    }
  }

  if (t < 224) {
    f32x4 sAcc = {0.f, 0.f, 0.f, 0.f}, qAcc = {0.f, 0.f, 0.f, 0.f};
    #pragma unroll
    for (int it = 0; it < 12; ++it) {
      const int cp = grp * 12 + it;
      const int c = cp >> 4, p1 = cp & 15;
      const int y = p1 * 14 + hi;
      const float* row = x + ((size_t)(b * 3 + c)) * 50176 + (size_t)y * 224;
      const f32x4 xv = *(const f32x4*)(row + x4);
      f32x4 ra = {0.f,0.f,0.f,0.f}, rb = {0.f,0.f,0.f,0.f};
      f32x4 la = {0.f,0.f,0.f,0.f}, lb = {0.f,0.f,0.f,0.f};
      if (q < 54) {
        ra = *(const f32x4*)(row + x4 + 8);
        if (y < 223) rb = *(const f32x4*)(row + x4 + 8 + 224);
      }
      if (q >= 2) {
        la = *(const f32x4*)(row + x4 - 8);
        if (y > 0) lb = *(const f32x4*)(row + x4 - 8 - 224);
      }
      const f32x4 rv = (1.0f - TW) * ra + TW * rb;
      const f32x4 lv = (1.0f - TW) * la + TW * lb;
      sAcc += xv + 2.0f * (lv + rv);
      qAcc += xv * xv + 2.0f * (lv * lv + rv * rv);
      const int kb = c * 256 + p1 * 16;
      #pragma unroll
      for (int j = 0; j < 4; ++j) {
        slab[sloff[j] + kb]        = f2bf(xv[j]);
        slab[sloff[j] + kb + 768]  = f2bf(lv[j]);
        slab[sloff[j] + kb + 1536] = f2bf(rv[j]);
      }
    }
    #pragma unroll
    for (int j = 0; j < 4; ++j) {
      sred[grp][x4 + j] = sAcc[j];
      qred[grp][x4 + j] = qAcc[j];
    }
  }
  __syncthreads();

  float ss = 0.f, qq = 0.f;
  if (t < 224) {
    ss = sred[0][t] + sred[1][t] + sred[2][t] + sred[3][t];
    qq = qred[0][t] + qred[1][t] + qred[2][t] + qred[3][t];
  }
  __syncthreads();
  if (t < 224) { sred[0][t] = ss; qred[0][t] = qq; }
  __syncthreads();

  const int tok0 = b * 196 + hi * 14;
  if (t < 14) {
    float S = 0.f, Q = 0.f;
    #pragma unroll
    for (int p = 0; p < 16; ++p) { S += sred[0][t + 14 * p]; Q += qred[0][t + 14 * p]; }
    const float mu = S / 3840.f;
    const float var = Q / 3840.f - mu * mu;
    const float r = rsqrtf(var + 1e-5f);
    stats[tok0 + t] = make_float2(r, -mu * r);
  }

  if (t < 224) {
    const int wi2 = t >> 4, sub = t & 15;
    const size_t vbase = (size_t)(tok0 + wi2) * 2304;
    #pragma unroll
    for (int cc = 0; cc < 18; ++cc) {
      const int off8 = (cc * 16 + sub) * 8;
      *(u16x8*)&V[vbase + off8] = *(const u16x8*)&slab[wi2 * 2312 + off8];
    }
  }
}

// ---------------------------------------------------------------------------
// Kernel 4: GEMM  out[m][j] = r_m * (V[m,:] . w2t[j,:]) + (-mu*r)_m * G[j] + Bt[j]
// 224x96 tile, BK=64, 4 waves (2M x 2N, each 112x48 out), double-buffered
// 80 KiB LDS -> 2 blocks/CU co-resident (inter-block stage/compute overlap).
// Counted s_waitcnt vmcnt(10) (7 A + 3 B loads per thread per stage), raw
// s_barrier, conflict-free XOR swizzle (byte ^= (row&7)<<4) via pre-swizzled
// global source. grid 448 = 56 m-tiles x 8 n-tiles, exact XCD swizzle (56/xcd),
// N-fastest so w2t is L2-resident per XCD and A-tiles are temporally shared.
// ---------------------------------------------------------------------------
__global__ __launch_bounds__(256, 2) void spt_gemm(
    const unsigned short* __restrict__ V, const unsigned short* __restrict__ w2t,
    const float2* __restrict__ stats, const float* __restrict__ G,
    const float* __restrict__ Bt, float* __restrict__ out)
{
  __shared__ unsigned short Alds[2][224 * 64];
  __shared__ unsigned short Blds[2][96 * 64];

  const int orig = blockIdx.x;
  const int wgid = (orig & 7) * 56 + (orig >> 3);  // exact: 448 = 8 * 56
  const int m0 = (wgid >> 3) * 224;
  const int n0 = (wgid & 7) * 96;
  const int t = threadIdx.x;
  const int w = t >> 6, l = t & 63;
  const int wr = w >> 1;   // 0..1 -> 112-row half
  const int wn = w & 1;    // 0..1 -> 48-col slice

  f32x4 acc[7][3] = {};

  // Staging: chunk c = i*256 + t covers row c>>3, 16B piece c&7 of a 64-el row.
  // Pre-swizzled source element offset so linear LDS dest + swizzled read agree.
#define STAGE(pb, kt)                                                          \
  {                                                                            \
    const int k0s = (kt) << 6;                                                 \
    _Pragma("unroll") for (int i = 0; i < 7; ++i) {                            \
      const int c = i * 256 + t;                                               \
      const int row = c >> 3;                                                  \
      const int srcel = (((c & 7) ^ (row & 7)) << 3);                          \
      const unsigned short* ga = V + (size_t)(m0 + row) * 2304 + k0s + srcel;  \
      __builtin_amdgcn_global_load_lds((const GLOBAL_AS unsigned int*)ga,      \
          (LDS_AS unsigned int*)&Alds[pb][i * 2048 + w * 512], 16, 0, 0);      \
    }                                                                          \
    _Pragma("unroll") for (int i = 0; i < 3; ++i) {                            \
      const int c = i * 256 + t;                                               \
      const int row = c >> 3;                                                  \
      const int srcel = (((c & 7) ^ (row & 7)) << 3);                          \
      const unsigned short* gb = w2t + (size_t)(n0 + row) * 2304 + k0s + srcel;\
      __builtin_amdgcn_global_load_lds((const GLOBAL_AS unsigned int*)gb,      \
          (LDS_AS unsigned int*)&Blds[pb][i * 2048 + w * 512], 16, 0, 0);      \
    }                                                                          \
  }

#define COMPUTE(pb)                                                            \
  {                                                                            \
    const int lane15 = l & 15;                                                 \
    const int kcol = (l >> 4) << 4;                                            \
    _Pragma("unroll") for (int kk = 0; kk < 2; ++kk) {                         \
      const int kb = kk * 64 + kcol;                                           \
      bf16x8 bF[3];                                                            \
      _Pragma("unroll") for (int n = 0; n < 3; ++n) {                          \
        const int row = wn * 48 + n * 16 + lane15;                             \
        const int phys = row * 128 + (kb ^ ((row & 7) << 4));                  \
        bF[n] = *(const bf16x8*)&Blds[pb][phys >> 1];                          \
      }                                                                        \
      _Pragma("unroll") for (int m = 0; m < 7; ++m) {                          \
        const int row = wr * 112 + m * 16 + lane15;                            \
        const int phys = row * 128 + (kb ^ ((row & 7) << 4));                  \
        const bf16x8 aF = *(const bf16x8*)&Alds[pb][phys >> 1];                \
        _Pragma("unroll") for (int n = 0; n < 3; ++n)                          \
          acc[m][n] = __builtin_amdgcn_mfma_f32_16x16x32_bf16(aF, bF[n],       \
                                                              acc[m][n], 0, 0, 0); \
      }                                                                        \
    }                                                                          \
  }

  STAGE(0, 0);
  int pb = 0;
  for (int kt = 0; kt < 35; ++kt) {
    STAGE(pb ^ 1, kt + 1);
    // wait for the 10 oldest loads (step kt); 10 newest (kt+1) stay in flight
    asm volatile("s_waitcnt vmcnt(10)\n\ts_barrier" ::: "memory");
    COMPUTE(pb);
    asm volatile("s_barrier" ::: "memory");  // reads of buf pb done before restage
    pb ^= 1;
  }
  asm volatile("s_waitcnt vmcnt(0)\n\ts_barrier" ::: "memory");
  COMPUTE(pb);

  // Epilogue: C/D frag layout col = l&15, row = (l>>4)*4 + reg
  const int lane15 = l & 15;
  const int lg = (l >> 4) * 4;
  #pragma unroll
  for (int m = 0; m < 7; ++m) {
    const int rowb = m0 + wr * 112 + m * 16 + lg;
    float2 st[4];
    #pragma unroll
    for (int r = 0; r < 4; ++r) st[r] = stats[rowb + r];
    #pragma unroll
    for (int n = 0; n < 3; ++n) {
      const int col = n0 + wn * 48 + n * 16 + lane15;
      const float Gc = G[col];
      const float Bc = Bt[col];
      #pragma unroll
      for (int r = 0; r < 4; ++r) {
        out[(size_t)(rowb + r) * 768 + col] = st[r].x * acc[m][n][r] + st[r].y * Gc + Bc;
      }
    }
  }
#undef STAGE
#undef COMPUTE
}

// ---------------------------------------------------------------------------
// Workspace layout (bytes):
//   V     : 0            57,802,752
//   w2t   : 57,802,752    3,538,944
//   stats : 61,341,696      100,352
//   G     : 61,442,048        3,072
//   Bt    : 61,445,120        3,072
//   Gp    : 61,448,192      442,368
//   Bp    : 61,890,560      442,368   -> total 62,332,928
// ---------------------------------------------------------------------------
extern "C" void kernel_launch(void* const* d_in, const int* in_sizes, int n_in,
                              void* d_out, int out_size, void* d_ws, size_t ws_size,
                              hipStream_t stream) {
  const float* x     = (const float*)d_in[0];
  const float* gamma = (const float*)d_in[1];
  const float* beta  = (const float*)d_in[2];
  const float* w     = (const float*)d_in[3];
  const float* bvec  = (const float*)d_in[4];
  float* out = (float*)d_out;

  char* ws = (char*)d_ws;
  unsigned short* V   = (unsigned short*)(ws);
  unsigned short* w2t = (unsigned short*)(ws + 57802752);
  float2* stats       = (float2*)(ws + 61341696);
  float* G            = (float*)(ws + 61442048);
  float* Bt           = (float*)(ws + 61445120);
  float* Gp           = (float*)(ws + 61448192);
  float* Bp           = (float*)(ws + 61890560);

  spt_pack<<<896, 256, 0, stream>>>(x, V, stats);
  spt_fold_w<<<dim3(144, 3), 256, 0, stream>>>(gamma, beta, w, w2t, Gp, Bp);
  spt_gb<<<3, 256, 0, stream>>>(Gp, Bp, bvec, G, Bt);
  spt_gemm<<<448, 256, 0, stream>>>(V, w2t, stats, G, Bt, out);
}